// Round 8
// baseline (381.236 us; speedup 1.0000x reference)
//
#include <hip/hip_runtime.h>
#include <math.h>

#define CDIM 256
#define CKD  32
#define NPIX 4096
#define BATCH 4
#define NMACRO (NPIX / 64)

typedef __attribute__((ext_vector_type(8)))  short bf16x8;
typedef __attribute__((ext_vector_type(16))) float f32x16;

__device__ inline ushort f2bf(float x) {
    unsigned u = __float_as_uint(x);
    u += 0x7fffu + ((u >> 16) & 1u);   // round-to-nearest-even
    return (ushort)(u >> 16);
}
__device__ inline unsigned packbf(float a, float b) {
    return (unsigned)f2bf(a) | ((unsigned)f2bf(b) << 16);
}

#define LDS_ASYNC16(gptr, lptr) \
  __builtin_amdgcn_global_load_lds((const __attribute__((address_space(1))) void*)(gptr), \
                                   (__attribute__((address_space(3))) void*)(lptr), 16, 0, 0)

// ---------------- Kernel 0: prep Wt[320][256] bf16 = [Wh^T; Wf^T; Wg^T] ----
// 2D LDS-tiled transpose: both global reads and writes coalesced.
__global__ __launch_bounds__(256) void prep_kernel(
    const float* __restrict__ Wh, const float* __restrict__ Wf,
    const float* __restrict__ Wg, ushort* __restrict__ Wt)
{
    __shared__ float ls[64 * 65];   // 16.6 KB
    const int tid = threadIdx.x;
    const int bid = blockIdx.x;

    if (bid < 16) {                 // Wh 64x64 tile transpose
        const int k0 = (bid & 3) * 64, c0 = (bid >> 2) * 64;
        #pragma unroll
        for (int i = 0; i < 16; ++i) {
            int r = i * 4 + (tid >> 6), c = tid & 63;
            ls[r * 65 + c] = Wh[(k0 + r) * 256 + c0 + c];   // coalesced 256B
        }
        __syncthreads();
        #pragma unroll
        for (int i = 0; i < 16; ++i) {
            int cr = i * 4 + (tid >> 6), k = tid & 63;
            Wt[(c0 + cr) * 256 + k0 + k] = f2bf(ls[k * 65 + cr]);  // coalesced
        }
    } else {                        // Wf/Wg [256k x 32c] -> Wt rows 256+
        const float* W = (bid == 16) ? Wf : Wg;
        const int rbase = 256 + (bid - 16) * 32;
        #pragma unroll
        for (int kh2 = 0; kh2 < 2; ++kh2) {
            __syncthreads();
            #pragma unroll
            for (int i = 0; i < 16; ++i) {
                int flat = i * 256 + tid;           // 0..4095
                int k = flat >> 5, c = flat & 31;
                ls[c * 129 + k] = W[(kh2 * 128 + k) * 32 + c];   // coalesced
            }
            __syncthreads();
            #pragma unroll
            for (int i = 0; i < 16; ++i) {
                int flat = i * 256 + tid;
                int c = flat >> 7, k = flat & 127;
                Wt[(rbase + c) * 256 + kh2 * 128 + k] = f2bf(ls[c * 129 + k]);
            }
        }
    }
}

// ---------------- Kernel 1: MFMA projections ------------------------------
// 512 blocks (2/CU), 4 waves, 32 px each. K=256, 8 slabs of 32, dbuf LDS.
// Wave w: hh c-rows w*64..+63 (D[row=c][col=px] -> tiled ht). Waves 0/1 also
// compute f/g. x loads now 8-lane-contiguous (128B bursts).
// wls chunk (n,o) at slot n*4 + ((o + (n>>1))&3)   [R6/R7-verified]
// xls chunk (px,o) at slot o*32 + ((px + 2o)&31)   [b64-write conflict-free]
__global__ __launch_bounds__(256) void proj_kernel(
    const float*  __restrict__ x,    // [B*N, 256] fp32
    const ushort* __restrict__ Wt,   // [320, 256] bf16
    const float*  __restrict__ bfp, const float* __restrict__ bgp,
    const float*  __restrict__ bhp,
    ushort* __restrict__ fo,         // bf16 [B*N, 32]
    ushort* __restrict__ go,         // bf16 [B*N, 32]
    ushort* __restrict__ glo,        // bf16 [B*N, 32]  g residual
    ushort* __restrict__ ht)         // bf16 [B*64][256][64] tiled values^T
{
    __shared__ ushort wls[2][1280 * 8];   // 20 KB each
    __shared__ ushort xls[2][128 * 8];    //  2 KB each

    const int tid  = threadIdx.x;
    const int w    = tid >> 6;
    const int lane = tid & 63;
    const int hl   = lane >> 5;
    const int ln   = lane & 31;
    const int bid  = blockIdx.x;
    const long long px0 = (long long)bid * 32;
    const int b    = (int)(px0 >> 12);
    const int n0   = (int)(px0 & (NPIX - 1));
    const int kt   = n0 >> 6;
    const int koff = n0 & 63;

    // x staging map: px = tid>>3 (row), quad j = tid&7 -> 8 lanes = 128B burst
    const int sx_px = tid >> 3, sx_j = tid & 7;
    const int sx_o = sx_j >> 1, sx_h = sx_j & 1;
    const int sx_slot = sx_o * 32 + ((sx_px + 2 * sx_o) & 31);

    // ---- stage slab 0
    #pragma unroll
    for (int i = 0; i < 5; ++i) {
        int s = i * 256 + tid;
        int n = s >> 2, o = ((s & 3) - (n >> 1)) & 3;
        LDS_ASYNC16(Wt + n * 256 + o * 8, &wls[0][s * 8]);
    }
    {
        float4 v = *(const float4*)(x + (px0 + sx_px) * CDIM + sx_j * 4);
        uint2 p; p.x = packbf(v.x, v.y); p.y = packbf(v.z, v.w);
        *(uint2*)&xls[0][sx_slot * 8 + sx_h * 4] = p;
    }

    f32x16 acc0={0,0,0,0,0,0,0,0,0,0,0,0,0,0,0,0};
    f32x16 acc1={0,0,0,0,0,0,0,0,0,0,0,0,0,0,0,0};
    f32x16 accfg={0,0,0,0,0,0,0,0,0,0,0,0,0,0,0,0};

    for (int sl = 0; sl < 8; ++sl) {
        const int cur = sl & 1;
        __syncthreads();
        if (sl + 1 < 8) {
            const int nxt = cur ^ 1;
            #pragma unroll
            for (int i = 0; i < 5; ++i) {
                int s = i * 256 + tid;
                int n = s >> 2, o = ((s & 3) - (n >> 1)) & 3;
                LDS_ASYNC16(Wt + n * 256 + (sl + 1) * 32 + o * 8, &wls[nxt][s * 8]);
            }
            float4 v = *(const float4*)(x + (px0 + sx_px) * CDIM + (sl + 1) * 32 + sx_j * 4);
            uint2 p; p.x = packbf(v.x, v.y); p.y = packbf(v.z, v.w);
            *(uint2*)&xls[nxt][sx_slot * 8 + sx_h * 4] = p;
        }

        #pragma unroll
        for (int st = 0; st < 2; ++st) {
            const int o = st * 2 + hl;
            #define LDW(n) (*(const bf16x8*)&wls[cur][((n) * 4 + (((o) + ((n) >> 1)) & 3)) * 8])
            bf16x8 xb  = *(const bf16x8*)&xls[cur][(o * 32 + ((ln + 2 * o) & 31)) * 8];
            bf16x8 wa0 = LDW(w * 64 + ln);
            bf16x8 wa1 = LDW(w * 64 + 32 + ln);
            acc0 = __builtin_amdgcn_mfma_f32_32x32x16_bf16(wa0, xb, acc0, 0, 0, 0);
            acc1 = __builtin_amdgcn_mfma_f32_32x32x16_bf16(wa1, xb, acc1, 0, 0, 0);
            if (w < 2) {
                bf16x8 wfg = LDW(256 + w * 32 + ln);
                accfg = __builtin_amdgcn_mfma_f32_32x32x16_bf16(xb, wfg, accfg, 0, 0, 0);
            }
            #undef LDW
        }
    }

    // ---- epilogue: hh -> tiled ht (coalesced 64B runs)
    ushort* htt = ht + ((long long)(b * 64 + kt) * CDIM) * 64 + koff;
    #pragma unroll
    for (int r = 0; r < 16; ++r) {
        const int rowD = (r & 3) + 8 * (r >> 2) + 4 * hl;
        int c0 = w * 64 + rowD, c1 = c0 + 32;
        htt[(long long)c0 * 64 + ln] = f2bf(acc0[r] + bhp[c0]);
        htt[(long long)c1 * 64 + ln] = f2bf(acc1[r] + bhp[c1]);
    }
    if (w < 2) {
        const float bb = (w ? bgp : bfp)[ln];
        #pragma unroll
        for (int r = 0; r < 16; ++r) {
            const int rowD = (r & 3) + 8 * (r >> 2) + 4 * hl;
            float v = accfg[r] + bb;
            ushort hi = f2bf(v);
            long long idx = (px0 + rowD) * CKD + ln;
            if (w == 0) {
                fo[idx] = hi;
            } else {
                go[idx] = hi;
                float hif = __uint_as_float(((unsigned)hi) << 16);
                glo[idx] = f2bf(v - hif);
            }
        }
    }
}

// ---------------- Kernel 2: MFMA attention, register-resident P -----------
// 512 blocks (2/CU), 4 waves. Block = 64 q x 128 ch (ch-split 2), 64-key
// macros, dbuf hh+f, ONE barrier per macro.
// Wave (qb=w&1, kh=w>>1): QK S^T(32k strip kh x 32q band qb); exp in regs;
// S^T C-layout -> PV A-frags via 2 x shfl_xor(32) quad swaps per K=16 chunk
// (NO LDS for P). PV: partial O[32q x 128c] over own 32-key strip only;
// kh pairs combined once at epilogue through LDS (hh_lds reused, 32 KB).
// hh chunk (c,j) at slot c*8+((j+c)&7); f chunk (key,j) at slot j*64+key.
__global__ __launch_bounds__(256, 2) void attn_kernel(
    const float*  __restrict__ x,
    const ushort* __restrict__ fk,   // bf16 [B*N,32] keys
    const ushort* __restrict__ gq,   // bf16 [B*N,32] queries (hi)
    const ushort* __restrict__ glo,  // bf16 [B*N,32] queries (lo residual)
    const ushort* __restrict__ hv,   // bf16 tiled [B*64][256][64] values^T
    float* __restrict__ out)
{
    __shared__ ushort hh_lds[2][1024 * 8];  // 16 KB each (reused as O_s fp32)
    __shared__ ushort f_lds[2][256 * 8];    //  4 KB each
    __shared__ float  l_red[2][64];

    const int tid  = threadIdx.x;
    const int w    = tid >> 6;
    const int lane = tid & 63;
    const int hl   = lane >> 5;
    const int ln   = lane & 31;

    const int bid = blockIdx.x;
    const int chs = bid & 1;
    const int b   = (bid >> 1) & 3;
    const int qt  = bid >> 3;            // 0..63
    const int q0  = qt * 64;

    const int qb = w & 1;                // q-band
    const int kh = w >> 1;               // key strip (QK+PV)

    const long long bbase = (long long)b * NPIX;
    const ushort* fbase = fk + bbase * CKD;
    const ushort* htb   = hv + (long long)b * 64 * (CDIM * 64);

    // g B-frags (hi+lo), registers all kernel
    const ushort* gp  = gq  + (bbase + q0 + qb * 32 + ln) * CKD;
    const ushort* glp = glo + (bbase + q0 + qb * 32 + ln) * CKD;
    const bf16x8 ga0 = *(const bf16x8*)(gp + hl * 8);
    const bf16x8 ga1 = *(const bf16x8*)(gp + 16 + hl * 8);
    const bf16x8 gl0 = *(const bf16x8*)(glp + hl * 8);
    const bf16x8 gl1 = *(const bf16x8*)(glp + 16 + hl * 8);

    // ---- stage macro 0 (lane-linear dests)
    #pragma unroll
    for (int i = 0; i < 4; ++i) {
        int s = i * 256 + tid;
        int c = s >> 3, j = ((s & 7) - c) & 7;
        LDS_ASYNC16(htb + (long long)(chs * 128 + c) * 64 + j * 8, &hh_lds[0][s * 8]);
    }
    LDS_ASYNC16(fbase + (long long)(tid & 63) * CKD + (tid >> 6) * 8, &f_lds[0][tid * 8]);

    f32x16 acc[4];
    #pragma unroll
    for (int t = 0; t < 4; ++t)
        acc[t] = (f32x16){0,0,0,0,0,0,0,0,0,0,0,0,0,0,0,0};
    float lsum = 0.f;

    for (int kt = 0; kt < NMACRO; ++kt) {
        const int cur = kt & 1;
        __syncthreads();   // staging(kt) drained; prev macro's LDS reads done

        // ---- stage macro kt+1 into other buffer (drains at next barrier)
        if (kt + 1 < NMACRO) {
            const int nxt = cur ^ 1;
            const long long tb = (long long)(kt + 1) * (CDIM * 64);
            #pragma unroll
            for (int i = 0; i < 4; ++i) {
                int s = i * 256 + tid;
                int c = s >> 3, j = ((s & 7) - c) & 7;
                LDS_ASYNC16(htb + tb + (long long)(chs * 128 + c) * 64 + j * 8,
                            &hh_lds[nxt][s * 8]);
            }
            LDS_ASYNC16(fbase + (long long)((kt + 1) * 64 + (tid & 63)) * CKD + (tid >> 6) * 8,
                        &f_lds[nxt][tid * 8]);
        }

        // ---- QK: S^T(32k x 32q) = f(A) . g(B), hi+lo
        f32x16 S={0,0,0,0,0,0,0,0,0,0,0,0,0,0,0,0};
        {
            bf16x8 fb0 = *(const bf16x8*)&f_lds[cur][((hl)     * 64 + kh * 32 + ln) * 8];
            bf16x8 fb1 = *(const bf16x8*)&f_lds[cur][((2 + hl) * 64 + kh * 32 + ln) * 8];
            S = __builtin_amdgcn_mfma_f32_32x32x16_bf16(fb0, ga0, S, 0, 0, 0);
            S = __builtin_amdgcn_mfma_f32_32x32x16_bf16(fb0, gl0, S, 0, 0, 0);
            S = __builtin_amdgcn_mfma_f32_32x32x16_bf16(fb1, ga1, S, 0, 0, 0);
            S = __builtin_amdgcn_mfma_f32_32x32x16_bf16(fb1, gl1, S, 0, 0, 0);
        }

        // ---- p = exp(s) in regs; pack to bf16 pairs
        float p[16];
        #pragma unroll
        for (int r = 0; r < 16; ++r) {
            p[r] = __expf(fminf(S[r], 80.f));
            lsum += p[r];
        }
        unsigned U[8];
        #pragma unroll
        for (int m = 0; m < 8; ++m) U[m] = packbf(p[2*m], p[2*m+1]);

        // ---- PV over own 32-key strip: A-frags via quad-swap shuffles
        #pragma unroll
        for (int ck = 0; ck < 2; ++ck) {
            // exchange: hl=0 sends rows 8..11 (U[4ck+2..3]), needs partner rows 4..7
            //           hl=1 sends rows 4..7 (U[4ck..+1]),  needs partner rows 8..11
            unsigned vx = hl ? U[4*ck]     : U[4*ck + 2];
            unsigned vy = hl ? U[4*ck + 1] : U[4*ck + 3];
            unsigned rx = (unsigned)__shfl_xor((int)vx, 32);
            unsigned ry = (unsigned)__shfl_xor((int)vy, 32);
            union { unsigned i[4]; bf16x8 v; } pf;
            pf.i[0] = hl ? rx : U[4*ck];
            pf.i[1] = hl ? ry : U[4*ck + 1];
            pf.i[2] = hl ? U[4*ck + 2] : rx;
            pf.i[3] = hl ? U[4*ck + 3] : ry;
            bf16x8 pa = pf.v;
            #pragma unroll
            for (int ct = 0; ct < 4; ++ct) {
                const int c = ct * 32 + ln;
                const int oct = kh * 4 + ck * 2 + hl;
                bf16x8 hb = *(const bf16x8*)&hh_lds[cur][(c * 8 + ((oct + c) & 7)) * 8];
                acc[ct] = __builtin_amdgcn_mfma_f32_32x32x16_bf16(pa, hb, acc[ct], 0, 0, 0);
            }
        }
    }

    // ---- combine kh pairs: l + O through LDS (hh_lds reused as fp32)
    lsum += __shfl_xor(lsum, 32);
    __syncthreads();                         // all PV reads retired
    if (hl == 0) l_red[kh][qb * 32 + ln] = lsum;
    float* O_s = (float*)hh_lds;             // [2qb][4ct][32q][32c] = 32 KB
    {
        const int wct0 = kh ? 0 : 2;         // ct's exported to partner
        #pragma unroll
        for (int t = 0; t < 2; ++t) {
            const int ct = wct0 + t;
            #pragma unroll
            for (int r = 0; r < 16; ++r) {
                int rowD = (r & 3) + 8 * (r >> 2) + 4 * hl;
                O_s[((qb * 4 + ct) * 32 + rowD) * 32 + ln] = acc[ct][r];
            }
        }
    }
    __syncthreads();

    // ---- epilogue: out = x + (own + partner)/l
    {
        const int oct0 = kh ? 2 : 0;         // ct's this wave outputs
        #pragma unroll
        for (int t = 0; t < 2; ++t) {
            const int ct = oct0 + t;
            #pragma unroll
            for (int r = 0; r < 16; ++r) {
                int rowD = (r & 3) + 8 * (r >> 2) + 4 * hl;
                int ql = qb * 32 + rowD;
                float linv = 1.f / (l_red[0][ql] + l_red[1][ql]);
                float o = acc[ct][r] + O_s[((qb * 4 + ct) * 32 + rowD) * 32 + ln];
                long long rg = (bbase + q0 + ql) * CDIM + chs * 128 + ct * 32 + ln;
                out[rg] = x[rg] + o * linv;
            }
        }
    }
}

extern "C" void kernel_launch(void* const* d_in, const int* in_sizes, int n_in,
                              void* d_out, int out_size, void* d_ws, size_t ws_size,
                              hipStream_t stream) {
    const float* x  = (const float*)d_in[0];
    const float* Wf = (const float*)d_in[1];
    const float* bf = (const float*)d_in[2];
    const float* Wg = (const float*)d_in[3];
    const float* bg = (const float*)d_in[4];
    const float* Wh = (const float*)d_in[5];
    const float* bh = (const float*)d_in[6];
    float* out = (float*)d_out;

    ushort* fbf = (ushort*)d_ws;                 // bf16 keys      [B*N,32]
    ushort* gbf = fbf + BATCH * NPIX * CKD;      // bf16 queries   [B*N,32]
    ushort* glo = gbf + BATCH * NPIX * CKD;      // bf16 q-residual[B*N,32]
    ushort* ht  = glo + BATCH * NPIX * CKD;      // bf16 tiled values^T
    ushort* Wt  = ht + BATCH * NPIX * CDIM;      // bf16 [320,256]

    prep_kernel<<<dim3(18), 256, 0, stream>>>(Wh, Wf, Wg, Wt);
    proj_kernel<<<dim3(512), 256, 0, stream>>>(x, Wt, bf, bg, bh, fbf, gbf, glo, ht);
    attn_kernel<<<dim3(512), 256, 0, stream>>>(x, fbf, gbf, glo, ht, out);
}

// Round 9
// 162.844 us; speedup vs baseline: 2.3411x; 2.3411x over previous
//
#include <hip/hip_runtime.h>
#include <math.h>

#define CDIM 256
#define CKD  32
#define NPIX 4096
#define BATCH 4
#define NMACRO (NPIX / 64)

typedef __attribute__((ext_vector_type(8)))  short bf16x8;
typedef __attribute__((ext_vector_type(16))) float f32x16;

__device__ inline ushort f2bf(float x) {
    unsigned u = __float_as_uint(x);
    u += 0x7fffu + ((u >> 16) & 1u);   // round-to-nearest-even
    return (ushort)(u >> 16);
}
__device__ inline unsigned packbf(float a, float b) {
    return (unsigned)f2bf(a) | ((unsigned)f2bf(b) << 16);
}

#define LDS_ASYNC16(gptr, lptr) \
  __builtin_amdgcn_global_load_lds((const __attribute__((address_space(1))) void*)(gptr), \
                                   (__attribute__((address_space(3))) void*)(lptr), 16, 0, 0)

// ---------------- Kernel 0: prep Wt[320][256] bf16 = [Wh^T; Wf^T; Wg^T] ----
__global__ __launch_bounds__(256) void prep_kernel(
    const float* __restrict__ Wh, const float* __restrict__ Wf,
    const float* __restrict__ Wg, ushort* __restrict__ Wt)
{
    __shared__ float ls[64 * 65];
    const int tid = threadIdx.x;
    const int bid = blockIdx.x;

    if (bid < 16) {                 // Wh 64x64 tile transpose
        const int k0 = (bid & 3) * 64, c0 = (bid >> 2) * 64;
        #pragma unroll
        for (int i = 0; i < 16; ++i) {
            int r = i * 4 + (tid >> 6), c = tid & 63;
            ls[r * 65 + c] = Wh[(k0 + r) * 256 + c0 + c];
        }
        __syncthreads();
        #pragma unroll
        for (int i = 0; i < 16; ++i) {
            int cr = i * 4 + (tid >> 6), k = tid & 63;
            Wt[(c0 + cr) * 256 + k0 + k] = f2bf(ls[k * 65 + cr]);
        }
    } else {                        // Wf/Wg [256k x 32c] -> Wt rows 256+
        const float* W = (bid == 16) ? Wf : Wg;
        const int rbase = 256 + (bid - 16) * 32;
        #pragma unroll
        for (int kh2 = 0; kh2 < 2; ++kh2) {
            __syncthreads();
            #pragma unroll
            for (int i = 0; i < 16; ++i) {
                int flat = i * 256 + tid;
                int k = flat >> 5, c = flat & 31;
                ls[c * 129 + k] = W[(kh2 * 128 + k) * 32 + c];
            }
            __syncthreads();
            #pragma unroll
            for (int i = 0; i < 16; ++i) {
                int flat = i * 256 + tid;
                int c = flat >> 7, k = flat & 127;
                Wt[(rbase + c) * 256 + kh2 * 128 + k] = f2bf(ls[c * 129 + k]);
            }
        }
    }
}

// ---------------- Kernel 1: MFMA projections ------------------------------
// 512 blocks (2/CU), 4 waves, 32 px each. K=256, 8 slabs of 32, dbuf LDS.
__global__ __launch_bounds__(256) void proj_kernel(
    const float*  __restrict__ x,    // [B*N, 256] fp32
    const ushort* __restrict__ Wt,   // [320, 256] bf16
    const float*  __restrict__ bfp, const float* __restrict__ bgp,
    const float*  __restrict__ bhp,
    ushort* __restrict__ fo,         // bf16 [B*N, 32]
    ushort* __restrict__ go,         // bf16 [B*N, 32]
    ushort* __restrict__ glo,        // bf16 [B*N, 32]  g residual
    ushort* __restrict__ ht)         // bf16 [B*64][256][64] tiled values^T
{
    __shared__ ushort wls[2][1280 * 8];
    __shared__ ushort xls[2][128 * 8];

    const int tid  = threadIdx.x;
    const int w    = tid >> 6;
    const int lane = tid & 63;
    const int hl   = lane >> 5;
    const int ln   = lane & 31;
    const int bid  = blockIdx.x;
    const long long px0 = (long long)bid * 32;
    const int b    = (int)(px0 >> 12);
    const int n0   = (int)(px0 & (NPIX - 1));
    const int kt   = n0 >> 6;
    const int koff = n0 & 63;

    const int sx_px = tid >> 3, sx_j = tid & 7;
    const int sx_o = sx_j >> 1, sx_h = sx_j & 1;
    const int sx_slot = sx_o * 32 + ((sx_px + 2 * sx_o) & 31);

    #pragma unroll
    for (int i = 0; i < 5; ++i) {
        int s = i * 256 + tid;
        int n = s >> 2, o = ((s & 3) - (n >> 1)) & 3;
        LDS_ASYNC16(Wt + n * 256 + o * 8, &wls[0][s * 8]);
    }
    {
        float4 v = *(const float4*)(x + (px0 + sx_px) * CDIM + sx_j * 4);
        uint2 p; p.x = packbf(v.x, v.y); p.y = packbf(v.z, v.w);
        *(uint2*)&xls[0][sx_slot * 8 + sx_h * 4] = p;
    }

    f32x16 acc0={0,0,0,0,0,0,0,0,0,0,0,0,0,0,0,0};
    f32x16 acc1={0,0,0,0,0,0,0,0,0,0,0,0,0,0,0,0};
    f32x16 accfg={0,0,0,0,0,0,0,0,0,0,0,0,0,0,0,0};

    for (int sl = 0; sl < 8; ++sl) {
        const int cur = sl & 1;
        __syncthreads();
        if (sl + 1 < 8) {
            const int nxt = cur ^ 1;
            #pragma unroll
            for (int i = 0; i < 5; ++i) {
                int s = i * 256 + tid;
                int n = s >> 2, o = ((s & 3) - (n >> 1)) & 3;
                LDS_ASYNC16(Wt + n * 256 + (sl + 1) * 32 + o * 8, &wls[nxt][s * 8]);
            }
            float4 v = *(const float4*)(x + (px0 + sx_px) * CDIM + (sl + 1) * 32 + sx_j * 4);
            uint2 p; p.x = packbf(v.x, v.y); p.y = packbf(v.z, v.w);
            *(uint2*)&xls[nxt][sx_slot * 8 + sx_h * 4] = p;
        }

        #pragma unroll
        for (int st = 0; st < 2; ++st) {
            const int o = st * 2 + hl;
            #define LDW(n) (*(const bf16x8*)&wls[cur][((n) * 4 + (((o) + ((n) >> 1)) & 3)) * 8])
            bf16x8 xb  = *(const bf16x8*)&xls[cur][(o * 32 + ((ln + 2 * o) & 31)) * 8];
            bf16x8 wa0 = LDW(w * 64 + ln);
            bf16x8 wa1 = LDW(w * 64 + 32 + ln);
            acc0 = __builtin_amdgcn_mfma_f32_32x32x16_bf16(wa0, xb, acc0, 0, 0, 0);
            acc1 = __builtin_amdgcn_mfma_f32_32x32x16_bf16(wa1, xb, acc1, 0, 0, 0);
            if (w < 2) {
                bf16x8 wfg = LDW(256 + w * 32 + ln);
                accfg = __builtin_amdgcn_mfma_f32_32x32x16_bf16(xb, wfg, accfg, 0, 0, 0);
            }
            #undef LDW
        }
    }

    ushort* htt = ht + ((long long)(b * 64 + kt) * CDIM) * 64 + koff;
    #pragma unroll
    for (int r = 0; r < 16; ++r) {
        const int rowD = (r & 3) + 8 * (r >> 2) + 4 * hl;
        int c0 = w * 64 + rowD, c1 = c0 + 32;
        htt[(long long)c0 * 64 + ln] = f2bf(acc0[r] + bhp[c0]);
        htt[(long long)c1 * 64 + ln] = f2bf(acc1[r] + bhp[c1]);
    }
    if (w < 2) {
        const float bb = (w ? bgp : bfp)[ln];
        #pragma unroll
        for (int r = 0; r < 16; ++r) {
            const int rowD = (r & 3) + 8 * (r >> 2) + 4 * hl;
            float v = accfg[r] + bb;
            ushort hi = f2bf(v);
            long long idx = (px0 + rowD) * CKD + ln;
            if (w == 0) {
                fo[idx] = hi;
            } else {
                go[idx] = hi;
                float hif = __uint_as_float(((unsigned)hi) << 16);
                glo[idx] = f2bf(v - hif);
            }
        }
    }
}

// ---------------- Kernel 2: MFMA attention, register-resident P -----------
// 512 blocks (2/CU), 4 waves. Block = 64 q x 128 ch (ch-split 2), 64-key
// macros, dbuf hh+f, ONE barrier per macro. NAMED accumulators acc0..acc3
// (NO arrays: dynamic indexing spills 64 VGPRs to scratch -> R8's 1.4 GB
// scratch traffic). Export/epilogue = wave-uniform branches on kh.
__global__ __launch_bounds__(256, 2) void attn_kernel(
    const float*  __restrict__ x,
    const ushort* __restrict__ fk,   // bf16 [B*N,32] keys
    const ushort* __restrict__ gq,   // bf16 [B*N,32] queries (hi)
    const ushort* __restrict__ glo,  // bf16 [B*N,32] queries (lo residual)
    const ushort* __restrict__ hv,   // bf16 tiled [B*64][256][64] values^T
    float* __restrict__ out)
{
    __shared__ ushort hh_lds[2][1024 * 8];  // 16 KB each (reused as O_s fp32)
    __shared__ ushort f_lds[2][256 * 8];    //  4 KB each
    __shared__ float  l_red[2][64];

    const int tid  = threadIdx.x;
    const int w    = tid >> 6;
    const int lane = tid & 63;
    const int hl   = lane >> 5;
    const int ln   = lane & 31;

    const int bid = blockIdx.x;
    const int chs = bid & 1;
    const int b   = (bid >> 1) & 3;
    const int qt  = bid >> 3;            // 0..63
    const int q0  = qt * 64;

    const int qb = w & 1;                // q-band
    const int kh = w >> 1;               // key strip (QK+PV)

    const long long bbase = (long long)b * NPIX;
    const ushort* fbase = fk + bbase * CKD;
    const ushort* htb   = hv + (long long)b * 64 * (CDIM * 64);

    const ushort* gp  = gq  + (bbase + q0 + qb * 32 + ln) * CKD;
    const ushort* glp = glo + (bbase + q0 + qb * 32 + ln) * CKD;
    const bf16x8 ga0 = *(const bf16x8*)(gp + hl * 8);
    const bf16x8 ga1 = *(const bf16x8*)(gp + 16 + hl * 8);
    const bf16x8 gl0 = *(const bf16x8*)(glp + hl * 8);
    const bf16x8 gl1 = *(const bf16x8*)(glp + 16 + hl * 8);

    #pragma unroll
    for (int i = 0; i < 4; ++i) {
        int s = i * 256 + tid;
        int c = s >> 3, j = ((s & 7) - c) & 7;
        LDS_ASYNC16(htb + (long long)(chs * 128 + c) * 64 + j * 8, &hh_lds[0][s * 8]);
    }
    LDS_ASYNC16(fbase + (long long)(tid & 63) * CKD + (tid >> 6) * 8, &f_lds[0][tid * 8]);

    f32x16 acc0={0,0,0,0,0,0,0,0,0,0,0,0,0,0,0,0};
    f32x16 acc1={0,0,0,0,0,0,0,0,0,0,0,0,0,0,0,0};
    f32x16 acc2={0,0,0,0,0,0,0,0,0,0,0,0,0,0,0,0};
    f32x16 acc3={0,0,0,0,0,0,0,0,0,0,0,0,0,0,0,0};
    float lsum = 0.f;

    for (int kt = 0; kt < NMACRO; ++kt) {
        const int cur = kt & 1;
        __syncthreads();   // staging(kt) drained; prev macro's LDS reads done

        // ---- stage macro kt+1 into other buffer (drains at next barrier)
        if (kt + 1 < NMACRO) {
            const int nxt = cur ^ 1;
            const long long tb = (long long)(kt + 1) * (CDIM * 64);
            #pragma unroll
            for (int i = 0; i < 4; ++i) {
                int s = i * 256 + tid;
                int c = s >> 3, j = ((s & 7) - c) & 7;
                LDS_ASYNC16(htb + tb + (long long)(chs * 128 + c) * 64 + j * 8,
                            &hh_lds[nxt][s * 8]);
            }
            LDS_ASYNC16(fbase + (long long)((kt + 1) * 64 + (tid & 63)) * CKD + (tid >> 6) * 8,
                        &f_lds[nxt][tid * 8]);
        }

        // ---- QK: S^T(32k x 32q) = f(A) . g(B), hi+lo
        f32x16 S={0,0,0,0,0,0,0,0,0,0,0,0,0,0,0,0};
        {
            bf16x8 fb0 = *(const bf16x8*)&f_lds[cur][((hl)     * 64 + kh * 32 + ln) * 8];
            bf16x8 fb1 = *(const bf16x8*)&f_lds[cur][((2 + hl) * 64 + kh * 32 + ln) * 8];
            S = __builtin_amdgcn_mfma_f32_32x32x16_bf16(fb0, ga0, S, 0, 0, 0);
            S = __builtin_amdgcn_mfma_f32_32x32x16_bf16(fb0, gl0, S, 0, 0, 0);
            S = __builtin_amdgcn_mfma_f32_32x32x16_bf16(fb1, ga1, S, 0, 0, 0);
            S = __builtin_amdgcn_mfma_f32_32x32x16_bf16(fb1, gl1, S, 0, 0, 0);
        }

        // ---- p = exp(s) in regs; pack to bf16 pairs
        float p[16];
        #pragma unroll
        for (int r = 0; r < 16; ++r) {
            p[r] = __expf(fminf(S[r], 80.f));
            lsum += p[r];
        }
        unsigned U[8];
        #pragma unroll
        for (int m = 0; m < 8; ++m) U[m] = packbf(p[2*m], p[2*m+1]);

        // ---- PV over own 32-key strip: A-frags via quad-swap shuffles
        #pragma unroll
        for (int ck = 0; ck < 2; ++ck) {
            unsigned vx = hl ? U[4*ck]     : U[4*ck + 2];
            unsigned vy = hl ? U[4*ck + 1] : U[4*ck + 3];
            unsigned rx = (unsigned)__shfl_xor((int)vx, 32);
            unsigned ry = (unsigned)__shfl_xor((int)vy, 32);
            union { unsigned i[4]; bf16x8 v; } pf;
            pf.i[0] = hl ? rx : U[4*ck];
            pf.i[1] = hl ? ry : U[4*ck + 1];
            pf.i[2] = hl ? U[4*ck + 2] : rx;
            pf.i[3] = hl ? U[4*ck + 3] : ry;
            bf16x8 pa = pf.v;
            const int oct = kh * 4 + ck * 2 + hl;
            const int c0 = ln, c1 = 32 + ln, c2 = 64 + ln, c3 = 96 + ln;
            bf16x8 hb0 = *(const bf16x8*)&hh_lds[cur][(c0 * 8 + ((oct + c0) & 7)) * 8];
            bf16x8 hb1 = *(const bf16x8*)&hh_lds[cur][(c1 * 8 + ((oct + c1) & 7)) * 8];
            bf16x8 hb2 = *(const bf16x8*)&hh_lds[cur][(c2 * 8 + ((oct + c2) & 7)) * 8];
            bf16x8 hb3 = *(const bf16x8*)&hh_lds[cur][(c3 * 8 + ((oct + c3) & 7)) * 8];
            acc0 = __builtin_amdgcn_mfma_f32_32x32x16_bf16(pa, hb0, acc0, 0, 0, 0);
            acc1 = __builtin_amdgcn_mfma_f32_32x32x16_bf16(pa, hb1, acc1, 0, 0, 0);
            acc2 = __builtin_amdgcn_mfma_f32_32x32x16_bf16(pa, hb2, acc2, 0, 0, 0);
            acc3 = __builtin_amdgcn_mfma_f32_32x32x16_bf16(pa, hb3, acc3, 0, 0, 0);
        }
    }

    // ---- combine kh pairs: l + O through LDS (hh_lds reused as fp32)
    lsum += __shfl_xor(lsum, 32);
    __syncthreads();                         // all PV reads retired
    if (hl == 0) l_red[kh][qb * 32 + ln] = lsum;
    float* O_s = (float*)hh_lds;             // [2qb][4ct][32q][32c] = 32 KB
    if (kh == 0) {                           // export ct 2,3
        #pragma unroll
        for (int r = 0; r < 16; ++r) {
            int rowD = (r & 3) + 8 * (r >> 2) + 4 * hl;
            O_s[((qb * 4 + 2) * 32 + rowD) * 32 + ln] = acc2[r];
            O_s[((qb * 4 + 3) * 32 + rowD) * 32 + ln] = acc3[r];
        }
    } else {                                 // export ct 0,1
        #pragma unroll
        for (int r = 0; r < 16; ++r) {
            int rowD = (r & 3) + 8 * (r >> 2) + 4 * hl;
            O_s[((qb * 4 + 0) * 32 + rowD) * 32 + ln] = acc0[r];
            O_s[((qb * 4 + 1) * 32 + rowD) * 32 + ln] = acc1[r];
        }
    }
    __syncthreads();

    // ---- epilogue: out = x + (own + partner)/l
    if (kh == 0) {                           // output ct 0,1
        #pragma unroll
        for (int r = 0; r < 16; ++r) {
            int rowD = (r & 3) + 8 * (r >> 2) + 4 * hl;
            int ql = qb * 32 + rowD;
            float linv = 1.f / (l_red[0][ql] + l_red[1][ql]);
            long long rg = (bbase + q0 + ql) * CDIM + chs * 128 + ln;
            float o0 = acc0[r] + O_s[((qb * 4 + 0) * 32 + rowD) * 32 + ln];
            float o1 = acc1[r] + O_s[((qb * 4 + 1) * 32 + rowD) * 32 + ln];
            out[rg]      = x[rg]      + o0 * linv;
            out[rg + 32] = x[rg + 32] + o1 * linv;
        }
    } else {                                 // output ct 2,3
        #pragma unroll
        for (int r = 0; r < 16; ++r) {
            int rowD = (r & 3) + 8 * (r >> 2) + 4 * hl;
            int ql = qb * 32 + rowD;
            float linv = 1.f / (l_red[0][ql] + l_red[1][ql]);
            long long rg = (bbase + q0 + ql) * CDIM + chs * 128 + 64 + ln;
            float o2 = acc2[r] + O_s[((qb * 4 + 2) * 32 + rowD) * 32 + ln];
            float o3 = acc3[r] + O_s[((qb * 4 + 3) * 32 + rowD) * 32 + ln];
            out[rg]      = x[rg]      + o2 * linv;
            out[rg + 32] = x[rg + 32] + o3 * linv;
        }
    }
}

extern "C" void kernel_launch(void* const* d_in, const int* in_sizes, int n_in,
                              void* d_out, int out_size, void* d_ws, size_t ws_size,
                              hipStream_t stream) {
    const float* x  = (const float*)d_in[0];
    const float* Wf = (const float*)d_in[1];
    const float* bf = (const float*)d_in[2];
    const float* Wg = (const float*)d_in[3];
    const float* bg = (const float*)d_in[4];
    const float* Wh = (const float*)d_in[5];
    const float* bh = (const float*)d_in[6];
    float* out = (float*)d_out;

    ushort* fbf = (ushort*)d_ws;                 // bf16 keys      [B*N,32]
    ushort* gbf = fbf + BATCH * NPIX * CKD;      // bf16 queries   [B*N,32]
    ushort* glo = gbf + BATCH * NPIX * CKD;      // bf16 q-residual[B*N,32]
    ushort* ht  = glo + BATCH * NPIX * CKD;      // bf16 tiled values^T
    ushort* Wt  = ht + BATCH * NPIX * CDIM;      // bf16 [320,256]

    prep_kernel<<<dim3(18), 256, 0, stream>>>(Wh, Wf, Wg, Wt);
    proj_kernel<<<dim3(512), 256, 0, stream>>>(x, Wt, bf, bg, bh, fbf, gbf, glo, ht);
    attn_kernel<<<dim3(512), 256, 0, stream>>>(x, fbf, gbf, glo, ht, out);
}